// Round 11
// baseline (980.767 us; speedup 1.0000x reference)
//
#include <hip/hip_runtime.h>
#include <math.h>

#define SD 7
#define HID 64
#define NITER 10

typedef float f4 __attribute__((ext_vector_type(4)));

// ---- DPP butterfly add over aligned 8-lane groups (r9-proven, pure VALU) ----
template<int CTRL>
__device__ __forceinline__ float dpp_add(float v) {
    int t = __builtin_amdgcn_update_dpp(0, __float_as_int(v), CTRL, 0xf, 0xf, true);
    return v + __int_as_float(t);
}
__device__ __forceinline__ float red8(float v) {
    v = dpp_add<0xB1>(v);   // quad_perm [1,0,3,2] : xor 1
    v = dpp_add<0x4E>(v);   // quad_perm [2,3,0,1] : xor 2
    v = dpp_add<0x141>(v);  // row_half_mirror     : combine the two quads
    return v;               // all 8 lanes hold the bit-identical total
}

// volatile LDS read blocks, wait inside (r9-proven pattern; no hoist, no reorder hazard)
#define LDS4(wa, wb, wc, wd, ADDR, O0, O1, O2, O3) \
    asm volatile("ds_read_b128 %0, %4 offset:" O0 "\n\t" \
                 "ds_read_b128 %1, %4 offset:" O1 "\n\t" \
                 "ds_read_b128 %2, %4 offset:" O2 "\n\t" \
                 "ds_read_b128 %3, %4 offset:" O3 "\n\t" \
                 "s_waitcnt lgkmcnt(0)" \
                 : "=&v"(wa), "=&v"(wb), "=&v"(wc), "=&v"(wd) : "v"(ADDR));

#define LDS2(wa, wb, ADDR, O0, O1) \
    asm volatile("ds_read_b128 %0, %2 offset:" O0 "\n\t" \
                 "ds_read_b128 %1, %2 offset:" O1 "\n\t" \
                 "s_waitcnt lgkmcnt(0)" \
                 : "=&v"(wa), "=&v"(wb) : "v"(ADDR));

// 8 FMAs of one fc0 weight row into xe (j ascending within lane)
#define FCROW(mk, wa, wb) { const float m_ = (mk); \
    xe[0]=fmaf(m_,(wa).x,xe[0]); xe[1]=fmaf(m_,(wa).y,xe[1]); \
    xe[2]=fmaf(m_,(wa).z,xe[2]); xe[3]=fmaf(m_,(wa).w,xe[3]); \
    xe[4]=fmaf(m_,(wb).x,xe[4]); xe[5]=fmaf(m_,(wb).y,xe[5]); \
    xe[6]=fmaf(m_,(wb).z,xe[6]); xe[7]=fmaf(m_,(wb).w,xe[7]); }

// fc0 row k=0 initializes xe from Be
#define FCROW0(wa, wb) { const float m_ = mu[0]; \
    xe[0]=fmaf(m_,(wa).x,Be[0]); xe[1]=fmaf(m_,(wa).y,Be[1]); \
    xe[2]=fmaf(m_,(wa).z,Be[2]); xe[3]=fmaf(m_,(wa).w,Be[3]); \
    xe[4]=fmaf(m_,(wb).x,Be[4]); xe[5]=fmaf(m_,(wb).y,Be[5]); \
    xe[6]=fmaf(m_,(wb).z,Be[6]); xe[7]=fmaf(m_,(wb).w,Be[7]); }

// out-matmul partial for output i over this lane's 8 j's (j ascending)
#define OROW(i, wa, wb) { \
    float p_ = xe[0]*(wa).x; \
    p_ = fmaf(xe[1],(wa).y,p_); p_ = fmaf(xe[2],(wa).z,p_); p_ = fmaf(xe[3],(wa).w,p_); \
    p_ = fmaf(xe[4],(wb).x,p_); p_ = fmaf(xe[5],(wb).y,p_); p_ = fmaf(xe[6],(wb).z,p_); \
    p_ = fmaf(xe[7],(wb).w,p_); pu[i] = p_; }

__global__ __launch_bounds__(256)
void strange_loop_kernel(const float* __restrict__ s7,
                         const float* __restrict__ w0,
                         const float* __restrict__ b0,
                         const float* __restrict__ lns,
                         const float* __restrict__ lnb,
                         const float* __restrict__ ow,
                         const float* __restrict__ ob,
                         float* __restrict__ out_mu,
                         float* __restrict__ out_cv,
                         int Bn)
{
    __shared__ __align__(16) float w0s[14 * HID];   // [14][64]   3584 B
    __shared__ __align__(16) float owT[SD * 72];    // [7][72]    2016 B (64 used + pad)

    const int tid = threadIdx.x;
    for (int idx = tid; idx < 14 * HID; idx += 256) w0s[idx] = w0[idx];
    for (int idx = tid; idx < HID * SD; idx += 256)
        owT[(idx % SD) * 72 + (idx / SD)] = ow[idx];   // owT[i][j] = ow[j][i]
    __syncthreads();

    const int lane = tid & 63;
    const int e    = lane & 7;          // lane owns j = 8e .. 8e+7 (contiguous)
    const int g    = lane >> 3;         // row within wave
    const int wave = tid >> 6;
    int row = (blockIdx.x * 4 + wave) * 8 + g;
    if (row >= Bn) row = Bn - 1;        // clamp: duplicate consistent work

    const unsigned aw0 = (unsigned)(size_t)(&w0s[0]) + (unsigned)(e * 32);
    const unsigned aow = (unsigned)(size_t)(&owT[0]) + (unsigned)(e * 32);

    // ---- one-time per-lane loads ----
    float s[SD];
    #pragma unroll
    for (int k = 0; k < SD; ++k) s[k] = s7[(size_t)row * SD + k];

    float Be[8];                        // b0 + ctx half of fc0 (k ascending)
    #pragma unroll
    for (int c = 0; c < 8; ++c) Be[c] = b0[8 * e + c];
    #pragma unroll
    for (int k = 0; k < SD; ++k) {
        const float sk = s[k];
        #pragma unroll
        for (int c = 0; c < 8; ++c)
            Be[c] = fmaf(sk, w0[(SD + k) * HID + 8 * e + c], Be[c]);
    }

    float ls[8], lb[8];                 // ln params for my 8 j's (persistent regs)
    #pragma unroll
    for (int c = 0; c < 8; ++c) { ls[c] = lns[8 * e + c]; lb[c] = lnb[8 * e + c]; }

    float obv[SD];
    #pragma unroll
    for (int i = 0; i < SD; ++i) obv[i] = ob[i];

    float mu[SD];
    #pragma unroll
    for (int i = 0; i < SD; ++i) mu[i] = 0.37796447300922720f;  // 1/sqrt(7)
    float conv = 0.0f;

    #pragma unroll 1
    for (int it = 0; it < NITER; ++it) {
        // ---- fc0: xe[c] = Be[c] + sum_k mu[k] * w0s[k][8e+c] ----
        float xe[8];
        {
            f4 wa, wb, wc, wd;
            LDS4(wa, wb, wc, wd, aw0, "0", "16", "256", "272")
            FCROW0(wa, wb) FCROW(mu[1], wc, wd)
            LDS4(wa, wb, wc, wd, aw0, "512", "528", "768", "784")
            FCROW(mu[2], wa, wb) FCROW(mu[3], wc, wd)
            LDS4(wa, wb, wc, wd, aw0, "1024", "1040", "1280", "1296")
            FCROW(mu[4], wa, wb) FCROW(mu[5], wc, wd)
            LDS2(wa, wb, aw0, "1536", "1552")
            FCROW(mu[6], wa, wb)
        }

        // ---- LayerNorm mean (local pairwise + DPP tree) ----
        float t01 = xe[0] + xe[1], t23 = xe[2] + xe[3];
        float t45 = xe[4] + xe[5], t67 = xe[6] + xe[7];
        float mean = red8((t01 + t23) + (t45 + t67)) * (1.0f / HID);

        // ---- variance ----
        float v0 = 0.f, v1 = 0.f;
        #pragma unroll
        for (int c = 0; c < 8; c += 2) {
            float a0 = xe[c] - mean, a1 = xe[c + 1] - mean;
            v0 = fmaf(a0, a0, v0); v1 = fmaf(a1, a1, v1);
            xe[c] = a0; xe[c + 1] = a1;
        }
        float var  = red8(v0 + v1) * (1.0f / HID);
        float rstd = 1.0f / sqrtf(var + 1e-6f);

        // ---- scale/shift + GELU (formula identical to all passing rounds) ----
        #pragma unroll
        for (int c = 0; c < 8; ++c) {
            float gx = fmaf(xe[c] * rstd, ls[c], lb[c]);
            float g2 = gx * gx;
            float g3 = g2 * gx;
            float z  = -1.5957691216057308f * fmaf(0.044715f, g3, gx);
            float ex = __expf(z);
            xe[c] = __fdividef(gx, 1.0f + ex);
        }

        // ---- out matmul partials: pu[i] over my 8 j's, owT rows from LDS ----
        float pu[SD];
        {
            f4 wa, wb, wc, wd;
            LDS4(wa, wb, wc, wd, aow, "0", "16", "288", "304")
            OROW(0, wa, wb) OROW(1, wc, wd)
            LDS4(wa, wb, wc, wd, aow, "576", "592", "864", "880")
            OROW(2, wa, wb) OROW(3, wc, wd)
            LDS4(wa, wb, wc, wd, aow, "1152", "1168", "1440", "1456")
            OROW(4, wa, wb) OROW(5, wc, wd)
            LDS2(wa, wb, aow, "1728", "1744")
            OROW(6, wa, wb)
        }

        // ---- reduce partials across the 8 lanes, add bias ----
        float u[SD];
        #pragma unroll
        for (int i = 0; i < SD; ++i) u[i] = red8(pu[i]) + obv[i];

        // ---- L2 normalize (identical) ----
        float ss = 0.f;
        #pragma unroll
        for (int i = 0; i < SD; ++i) ss = fmaf(u[i], u[i], ss);
        float inv = __fdividef(1.0f, sqrtf(ss) + 1e-8f);

        // ---- damped update + convergence (identical) ----
        float dd = 0.f;
        #pragma unroll
        for (int i = 0; i < SD; ++i) {
            float un = u[i] * inv;
            float mn = 0.5f * mu[i] + 0.5f * un;
            float d  = mn - mu[i];
            dd = fmaf(d, d, dd);
            mu[i] = mn;
        }
        if (sqrtf(dd) < 1e-4f) conv = 1.0f;
    }

    // lane e<7 stores mu[e]; lane e==7 stores conv (all lanes hold identical mu)
    float val = mu[0];
    val = (e == 1) ? mu[1] : val;
    val = (e == 2) ? mu[2] : val;
    val = (e == 3) ? mu[3] : val;
    val = (e == 4) ? mu[4] : val;
    val = (e == 5) ? mu[5] : val;
    val = (e == 6) ? mu[6] : val;
    if (e < SD) out_mu[(size_t)row * SD + e] = val;
    else        out_cv[row] = conv;
}

extern "C" void kernel_launch(void* const* d_in, const int* in_sizes, int n_in,
                              void* d_out, int out_size, void* d_ws, size_t ws_size,
                              hipStream_t stream) {
    const float* s7  = (const float*)d_in[0];
    const float* w0  = (const float*)d_in[1];
    const float* b0  = (const float*)d_in[2];
    const float* lns = (const float*)d_in[3];
    const float* lnb = (const float*)d_in[4];
    const float* ow  = (const float*)d_in[5];
    const float* ob  = (const float*)d_in[6];
    const int Bn = in_sizes[0] / SD;

    float* out_mu = (float*)d_out;
    float* out_cv = out_mu + (size_t)Bn * SD;

    // 8 lanes per row -> 32 rows per 256-thread block
    const int block = 256;
    const int grid  = (Bn + 31) / 32;
    hipLaunchKernelGGL(strange_loop_kernel, dim3(grid), dim3(block), 0, stream,
                       s7, w0, b0, lns, lnb, ow, ob, out_mu, out_cv, Bn);
}

// Round 12
// 597.685 us; speedup vs baseline: 1.6409x; 1.6409x over previous
//
#include <hip/hip_runtime.h>
#include <math.h>

#define SD 7
#define HID 64
#define NITER 10

typedef float f16s __attribute__((ext_vector_type(16)));
typedef float f8s  __attribute__((ext_vector_type(8)));
typedef float f4   __attribute__((ext_vector_type(4)));
typedef float f2   __attribute__((ext_vector_type(2)));

#define REP4(M)  M(0) M(1) M(2) M(3)
#define REP7(M)  M(0) M(1) M(2) M(3) M(4) M(5) M(6)
#define REP15(M) M(1) M(2) M(3) M(4) M(5) M(6) M(7) M(8) M(9) M(10) M(11) M(12) M(13) M(14) M(15)
#define REP16(M) M(0) M(1) M(2) M(3) M(4) M(5) M(6) M(7) M(8) M(9) M(10) M(11) M(12) M(13) M(14) M(15)
#define AP8(M, ...) M(0, __VA_ARGS__) M(1, __VA_ARGS__) M(2, __VA_ARGS__) M(3, __VA_ARGS__) \
    M(4, __VA_ARGS__) M(5, __VA_ARGS__) M(6, __VA_ARGS__) M(7, __VA_ARGS__)
#define AP16(M, ...) M(0, __VA_ARGS__) M(1, __VA_ARGS__) M(2, __VA_ARGS__) M(3, __VA_ARGS__) \
    M(4, __VA_ARGS__) M(5, __VA_ARGS__) M(6, __VA_ARGS__) M(7, __VA_ARGS__) \
    M(8, __VA_ARGS__) M(9, __VA_ARGS__) M(10, __VA_ARGS__) M(11, __VA_ARGS__) \
    M(12, __VA_ARGS__) M(13, __VA_ARGS__) M(14, __VA_ARGS__) M(15, __VA_ARGS__)

// ---- SMEM loads (r4-proven): uniform weights -> SGPRs, volatile => no hoist ----
#define SLOAD4(d0, d1, d2, d3, p, o0, o1, o2, o3) \
    asm volatile("s_load_dwordx16 %0, %4, %5\n\t" \
                 "s_load_dwordx16 %1, %4, %6\n\t" \
                 "s_load_dwordx16 %2, %4, %7\n\t" \
                 "s_load_dwordx16 %3, %4, %8\n\t" \
                 "s_waitcnt lgkmcnt(0)" \
                 : "=&s"(d0), "=&s"(d1), "=&s"(d2), "=&s"(d3) \
                 : "s"(p), "i"(o0), "i"(o1), "i"(o2), "i"(o3));

#define SLD16(d, obytes, p) \
    asm volatile("s_load_dwordx16 %0, %1, %2\n\t" \
                 "s_waitcnt lgkmcnt(0)" \
                 : "=&s"(d) : "s"(p), "i"(obytes));

#define SLOADX8(d0, p) \
    asm volatile("s_load_dwordx8 %0, %1, 0\n\t" \
                 "s_waitcnt lgkmcnt(0)" \
                 : "=&s"(d0) : "s"(p));

// ---- LDS uniform batched read (r10-proven): 4 x b128, wait inside ----
#define LDS4U(wa, wb, wc, wd, ADDR) \
    asm volatile("ds_read_b128 %0, %4 offset:0\n\t" \
                 "ds_read_b128 %1, %4 offset:16\n\t" \
                 "ds_read_b128 %2, %4 offset:32\n\t" \
                 "ds_read_b128 %3, %4 offset:48\n\t" \
                 "s_waitcnt lgkmcnt(0)" \
                 : "=&v"(wa), "=&v"(wb), "=&v"(wc), "=&v"(wd) : "v"(ADDR));

// ---- pk helpers: even-aligned pair subviews (no recompose movs expected) ----
#define PKW(W, e)   __builtin_shufflevector((W), (W), 2*(e), 2*(e)+1)
#define SHF2(V, h_) __builtin_shufflevector((V), (V), 2*(h_), 2*(h_)+1)

// dst/acc VGPR pair; w from SGPR pair (1 sgpr read); per-half rounding == v_fma_f32
#define PKFMA_ACC(acc, ws, mv) \
    asm("v_pk_fma_f32 %0, %1, %2, %0" : "+v"(acc) : "s"(ws), "v"(mv));
#define PKFMA_NEW(dst, ws, mv, cv) \
    asm("v_pk_fma_f32 %0, %1, %2, %3" : "=v"(dst) : "s"(ws), "v"(mv), "v"(cv));
#define PKFMA_GL(g, tv, lss, lbv) \
    asm("v_pk_fma_f32 %0, %1, %2, %3" : "=v"(g) : "v"(tv), "s"(lss), "v"(lbv));

// one packed fc0 row chunk: arr[base+e] += W.pair(e) * m2
#define PKROW_E(e, arr, base, m2v, W) PKFMA_ACC((arr)[(base)+(e)], PKW(W, e), m2v)
#define PKROW(arr, m2v, wa, wb, wc, wd) \
    AP8(PKROW_E, arr, 0,  m2v, wa) AP8(PKROW_E, arr, 8,  m2v, wb) \
    AP8(PKROW_E, arr, 16, m2v, wc) AP8(PKROW_E, arr, 24, m2v, wd)

__global__ __launch_bounds__(256) __attribute__((amdgpu_waves_per_eu(2)))
void strange_loop_kernel(const float* __restrict__ s7,
                         const float* __restrict__ w0,
                         const float* __restrict__ b0,
                         const float* __restrict__ lns,
                         const float* __restrict__ lnb,
                         const float* __restrict__ ow,
                         const float* __restrict__ ob,
                         float* __restrict__ out_mu,
                         float* __restrict__ out_cv,
                         int Bn)
{
    __shared__ __align__(16) float lnp[HID];     // lnb staged in LDS (VGPR-pair source)
    const int tid = threadIdx.x;
    if (tid < HID) lnp[tid] = lnb[tid];
    __syncthreads();

    const unsigned alnb = (unsigned)(size_t)(&lnp[0]);
    const unsigned aln0 = alnb, aln1 = alnb + 64, aln2 = alnb + 128, aln3 = alnb + 192;

    int row = blockIdx.x * blockDim.x + tid;
    if (row >= Bn) row = Bn - 1;   // clamp: uniform control flow, dup write benign

    float s[SD];
#define LD_S(k) s[k] = s7[(size_t)row * SD + (k)];
    REP7(LD_S)

    // ---- iteration-invariant: Be2 = b0 + sum_k s[k]*W0[7+k][.] (packed pairs) ----
    f2 Be2[32];
    {
        f16s ba, bb, bc, bd;
        SLOAD4(ba, bb, bc, bd, b0, 0, 64, 128, 192)
#define B0P(e, W, base) Be2[(base)+(e)] = PKW(W, e);
        AP8(B0P, ba, 0) AP8(B0P, bb, 8) AP8(B0P, bc, 16) AP8(B0P, bd, 24)
    }
#define BIK(k) { f16s wa, wb, wc, wd; \
    SLOAD4(wa, wb, wc, wd, w0, (7+(k))*256, (7+(k))*256+64, (7+(k))*256+128, (7+(k))*256+192) \
    f2 m2 = {s[k], s[k]}; \
    PKROW(Be2, m2, wa, wb, wc, wd) }
    REP7(BIK)

    f8s obv;
    SLOADX8(obv, ob)

    float mu[SD];
#define INITMU(i) mu[i] = 0.37796447300922720f;   // 1/sqrt(7)
    REP7(INITMU)
    float conv = 0.0f;

#pragma unroll 1
    for (int it = 0; it < NITER; ++it) {
        // ---- fc0 packed: xe2 = Be2 + sum_k mu[k]*W0[k][.]; k=0 writes fresh ----
        f2 xe2[32];
        { f16s wa, wb, wc, wd;
          SLOAD4(wa, wb, wc, wd, w0, 0, 64, 128, 192)
          f2 m2 = {mu[0], mu[0]};
#define FC00_E(e, W, base) PKFMA_NEW(xe2[(base)+(e)], PKW(W, e), m2, Be2[(base)+(e)])
          AP8(FC00_E, wa, 0) AP8(FC00_E, wb, 8) AP8(FC00_E, wc, 16) AP8(FC00_E, wd, 24)
        }
#define FC0K(k) { f16s wa, wb, wc, wd; \
        SLOAD4(wa, wb, wc, wd, w0, (k)*256, (k)*256+64, (k)*256+128, (k)*256+192) \
        f2 m2 = {mu[k], mu[k]}; \
        PKROW(xe2, m2, wa, wb, wc, wd) }
        FC0K(1) FC0K(2) FC0K(3) FC0K(4) FC0K(5) FC0K(6)

        // ---- LayerNorm (r7-proven packed two-pass) ----
        f2 P01 = xe2[0], P23 = xe2[1];
#define SACE(q) P01 += xe2[2*(q)]; P23 += xe2[2*(q)+1];
        REP15(SACE)
        float mean = ((P01.x + P01.y) + (P23.x + P23.y)) * (1.0f / HID);

        f2 V01 = {0.f, 0.f}, V23 = {0.f, 0.f};
        {
            f2 mn2 = {mean, mean};
#define VACE(q) { f2 a0 = xe2[2*(q)] - mn2; f2 a1 = xe2[2*(q)+1] - mn2; \
            V01 = __builtin_elementwise_fma(a0, a0, V01); \
            V23 = __builtin_elementwise_fma(a1, a1, V23); \
            xe2[2*(q)] = a0; xe2[2*(q)+1] = a1; }
            REP16(VACE)
        }
        float var  = ((V01.x + V01.y) + (V23.x + V23.y)) * (1.0f / HID);
        float rstd = 1.0f / sqrtf(var + 1e-6f);

        // ---- scale/shift + GELU, packed polynomial (per-half ops identical) ----
        {
            const f2 rs2 = {rstd, rstd};
            const f2 kB2 = {0.044715f, 0.044715f};
            const f2 kC2 = {-1.5957691216057308f, -1.5957691216057308f};
#define GEL1(p, lss, lbv) { \
            f2 t = xe2[p] * rs2; \
            f2 g; PKFMA_GL(g, t, lss, lbv) \
            f2 g2 = g * g; f2 g3 = g2 * g; \
            f2 z = __builtin_elementwise_fma(kB2, g3, g) * kC2; \
            float e0 = __expf(z.x), e1 = __expf(z.y); \
            xe2[p].x = __fdividef(g.x, 1.0f + e0); \
            xe2[p].y = __fdividef(g.y, 1.0f + e1); }
#define GELH(h, AH) { f16s lsg; SLD16(lsg, (h)*64, lns) \
            f4 L0, L1, L2, L3; LDS4U(L0, L1, L2, L3, AH) \
            GEL1(8*(h)+0, PKW(lsg,0), SHF2(L0,0)) \
            GEL1(8*(h)+1, PKW(lsg,1), SHF2(L0,1)) \
            GEL1(8*(h)+2, PKW(lsg,2), SHF2(L1,0)) \
            GEL1(8*(h)+3, PKW(lsg,3), SHF2(L1,1)) \
            GEL1(8*(h)+4, PKW(lsg,4), SHF2(L2,0)) \
            GEL1(8*(h)+5, PKW(lsg,5), SHF2(L2,1)) \
            GEL1(8*(h)+6, PKW(lsg,6), SHF2(L3,0)) \
            GEL1(8*(h)+7, PKW(lsg,7), SHF2(L3,1)) }
            GELH(0, aln0) GELH(1, aln1) GELH(2, aln2) GELH(3, aln3)
        }

        // ---- out matmul [1x64]x[64x7] (r4-verbatim scalar, flat ascending) ----
        float u[SD];
#define IU(i) u[i] = obv[i];
        REP7(IU)
#define XE(f) (((f)%2==0) ? xe2[(f)/2].x : xe2[(f)/2].y)
#define OUTE(e, m, W) u[(16*(m)+(e))%7] = fmaf(XE((16*(m)+(e))/7), (W)[(e)], u[(16*(m)+(e))%7]);
#define OUTG(g) { f16s a0, a1, a2, a3; \
        SLOAD4(a0, a1, a2, a3, ow, (g)*256, (g)*256+64, (g)*256+128, (g)*256+192) \
        AP16(OUTE, 4*(g)+0, a0) AP16(OUTE, 4*(g)+1, a1) \
        AP16(OUTE, 4*(g)+2, a2) AP16(OUTE, 4*(g)+3, a3) }
        REP7(OUTG)

        // ---- L2 normalize (identical) ----
        float ss = 0.f;
#define SSQ(i) ss = fmaf(u[i], u[i], ss);
        REP7(SSQ)
        float inv = __fdividef(1.0f, sqrtf(ss) + 1e-8f);

        // ---- damped update + convergence (identical) ----
        float dd = 0.f;
#define UPD(i) { float un = u[i] * inv; float mn = 0.5f * mu[i] + 0.5f * un; \
        float d = mn - mu[i]; dd = fmaf(d, d, dd); mu[i] = mn; }
        REP7(UPD)
        if (sqrtf(dd) < 1e-4f) conv = 1.0f;
    }

#define ST(i) out_mu[(size_t)row * SD + (i)] = mu[i];
    REP7(ST)
    out_cv[row] = conv;
}

extern "C" void kernel_launch(void* const* d_in, const int* in_sizes, int n_in,
                              void* d_out, int out_size, void* d_ws, size_t ws_size,
                              hipStream_t stream) {
    const float* s7  = (const float*)d_in[0];
    const float* w0  = (const float*)d_in[1];
    const float* b0  = (const float*)d_in[2];
    const float* lns = (const float*)d_in[3];
    const float* lnb = (const float*)d_in[4];
    const float* ow  = (const float*)d_in[5];
    const float* ob  = (const float*)d_in[6];
    const int Bn = in_sizes[0] / SD;

    float* out_mu = (float*)d_out;
    float* out_cv = out_mu + (size_t)Bn * SD;

    const int block = 256;
    const int grid  = (Bn + block - 1) / block;
    hipLaunchKernelGGL(strange_loop_kernel, dim3(grid), dim3(block), 0, stream,
                       s7, w0, b0, lns, lnb, ow, ob, out_mu, out_cv, Bn);
}

// Round 13
// 593.018 us; speedup vs baseline: 1.6539x; 1.0079x over previous
//
#include <hip/hip_runtime.h>
#include <math.h>

#define SD 7
#define HID 64
#define NITER 10

typedef float f16s __attribute__((ext_vector_type(16)));
typedef float f8s  __attribute__((ext_vector_type(8)));
typedef float f4   __attribute__((ext_vector_type(4)));
typedef float f2   __attribute__((ext_vector_type(2)));

#define REP4(M)  M(0) M(1) M(2) M(3)
#define REP7(M)  M(0) M(1) M(2) M(3) M(4) M(5) M(6)
#define REP15(M) M(1) M(2) M(3) M(4) M(5) M(6) M(7) M(8) M(9) M(10) M(11) M(12) M(13) M(14) M(15)
#define REP16(M) M(0) M(1) M(2) M(3) M(4) M(5) M(6) M(7) M(8) M(9) M(10) M(11) M(12) M(13) M(14) M(15)
#define AP8(M, ...) M(0, __VA_ARGS__) M(1, __VA_ARGS__) M(2, __VA_ARGS__) M(3, __VA_ARGS__) \
    M(4, __VA_ARGS__) M(5, __VA_ARGS__) M(6, __VA_ARGS__) M(7, __VA_ARGS__)

// ---- SMEM loads (r4/r11-proven): uniform weights -> SGPRs, volatile => no hoist ----
#define SLOAD4(d0, d1, d2, d3, p, o0, o1, o2, o3) \
    asm volatile("s_load_dwordx16 %0, %4, %5\n\t" \
                 "s_load_dwordx16 %1, %4, %6\n\t" \
                 "s_load_dwordx16 %2, %4, %7\n\t" \
                 "s_load_dwordx16 %3, %4, %8\n\t" \
                 "s_waitcnt lgkmcnt(0)" \
                 : "=&s"(d0), "=&s"(d1), "=&s"(d2), "=&s"(d3) \
                 : "s"(p), "i"(o0), "i"(o1), "i"(o2), "i"(o3));

#define SLD16(d, obytes, p) \
    asm volatile("s_load_dwordx16 %0, %1, %2\n\t" \
                 "s_waitcnt lgkmcnt(0)" \
                 : "=&s"(d) : "s"(p), "i"(obytes));

#define SLOADX8(d0, p) \
    asm volatile("s_load_dwordx8 %0, %1, 0\n\t" \
                 "s_waitcnt lgkmcnt(0)" \
                 : "=&s"(d0) : "s"(p));

// ---- LDS uniform batched read (r10/r11-proven): 4 x b128, wait inside ----
#define LDS4U(wa, wb, wc, wd, ADDR) \
    asm volatile("ds_read_b128 %0, %4 offset:0\n\t" \
                 "ds_read_b128 %1, %4 offset:16\n\t" \
                 "ds_read_b128 %2, %4 offset:32\n\t" \
                 "ds_read_b128 %3, %4 offset:48\n\t" \
                 "s_waitcnt lgkmcnt(0)" \
                 : "=&v"(wa), "=&v"(wb), "=&v"(wc), "=&v"(wd) : "v"(ADDR));

// ---- pk helpers: even-aligned pair subviews ----
#define PKW(W, e)   __builtin_shufflevector((W), (W), 2*(e), 2*(e)+1)
#define SHF2(V, h_) __builtin_shufflevector((V), (V), 2*(h_), 2*(h_)+1)

#define PKFMA_ACC(acc, ws, mv) \
    asm("v_pk_fma_f32 %0, %1, %2, %0" : "+v"(acc) : "s"(ws), "v"(mv));
#define PKFMA_NEW(dst, ws, mv, cv) \
    asm("v_pk_fma_f32 %0, %1, %2, %3" : "=v"(dst) : "s"(ws), "v"(mv), "v"(cv));
#define PKFMA_GL(g, tv, lss, lbv) \
    asm("v_pk_fma_f32 %0, %1, %2, %3" : "=v"(g) : "v"(tv), "s"(lss), "v"(lbv));

#define PKROW_E(e, arr, base, m2v, W) PKFMA_ACC((arr)[(base)+(e)], PKW(W, e), m2v)
#define PKROW(arr, m2v, wa, wb, wc, wd) \
    AP8(PKROW_E, arr, 0,  m2v, wa) AP8(PKROW_E, arr, 8,  m2v, wb) \
    AP8(PKROW_E, arr, 16, m2v, wc) AP8(PKROW_E, arr, 24, m2v, wd)

// out-matmul: acc2 += xe2[pair] * owT-pair (weights from SGPRs)
#define OPK_E(e, acc, base, W) PKFMA_ACC(acc, PKW(W, e), xe2[(base)+(e)])

__global__ void transpose_ow_kernel(const float* __restrict__ ow,
                                    float* __restrict__ owt) {
    int t = threadIdx.x;
    if (t < HID * SD) owt[(t % SD) * HID + (t / SD)] = ow[t];   // owT[i][j]
}

__global__ __launch_bounds__(256) __attribute__((amdgpu_waves_per_eu(2)))
void strange_loop_kernel(const float* __restrict__ s7,
                         const float* __restrict__ w0,
                         const float* __restrict__ b0,
                         const float* __restrict__ lns,
                         const float* __restrict__ lnb,
                         const float* __restrict__ owt,
                         const float* __restrict__ ob,
                         float* __restrict__ out_mu,
                         float* __restrict__ out_cv,
                         int Bn)
{
    __shared__ __align__(16) float lnp[HID];     // lnb staged in LDS (VGPR-pair source)
    const int tid = threadIdx.x;
    if (tid < HID) lnp[tid] = lnb[tid];
    __syncthreads();

    const unsigned alnb = (unsigned)(size_t)(&lnp[0]);
    const unsigned aln0 = alnb, aln1 = alnb + 64, aln2 = alnb + 128, aln3 = alnb + 192;

    int row = blockIdx.x * blockDim.x + tid;
    if (row >= Bn) row = Bn - 1;   // clamp: uniform control flow, dup write benign

    float s[SD];
#define LD_S(k) s[k] = s7[(size_t)row * SD + (k)];
    REP7(LD_S)

    // ---- iteration-invariant: Be2 = b0 + sum_k s[k]*W0[7+k][.] (packed pairs) ----
    f2 Be2[32];
    {
        f16s ba, bb, bc, bd;
        SLOAD4(ba, bb, bc, bd, b0, 0, 64, 128, 192)
#define B0P(e, W, base) Be2[(base)+(e)] = PKW(W, e);
        AP8(B0P, ba, 0) AP8(B0P, bb, 8) AP8(B0P, bc, 16) AP8(B0P, bd, 24)
    }
#define BIK(k) { f16s wa, wb, wc, wd; \
    SLOAD4(wa, wb, wc, wd, w0, (7+(k))*256, (7+(k))*256+64, (7+(k))*256+128, (7+(k))*256+192) \
    f2 m2 = {s[k], s[k]}; \
    PKROW(Be2, m2, wa, wb, wc, wd) }
    REP7(BIK)

    f8s obv;
    SLOADX8(obv, ob)

    float mu[SD];
#define INITMU(i) mu[i] = 0.37796447300922720f;   // 1/sqrt(7)
    REP7(INITMU)
    float conv = 0.0f;

#pragma unroll 1
    for (int it = 0; it < NITER; ++it) {
        // ---- fc0 packed: xe2 = Be2 + sum_k mu[k]*W0[k][.]; k=0 writes fresh ----
        f2 xe2[32];
        { f16s wa, wb, wc, wd;
          SLOAD4(wa, wb, wc, wd, w0, 0, 64, 128, 192)
          f2 m2 = {mu[0], mu[0]};
#define FC00_E(e, W, base) PKFMA_NEW(xe2[(base)+(e)], PKW(W, e), m2, Be2[(base)+(e)])
          AP8(FC00_E, wa, 0) AP8(FC00_E, wb, 8) AP8(FC00_E, wc, 16) AP8(FC00_E, wd, 24)
        }
#define FC0K(k) { f16s wa, wb, wc, wd; \
        SLOAD4(wa, wb, wc, wd, w0, (k)*256, (k)*256+64, (k)*256+128, (k)*256+192) \
        f2 m2 = {mu[k], mu[k]}; \
        PKROW(xe2, m2, wa, wb, wc, wd) }
        FC0K(1) FC0K(2) FC0K(3) FC0K(4) FC0K(5) FC0K(6)

        // ---- LayerNorm (r7/r11-proven packed two-pass) ----
        f2 P01 = xe2[0], P23 = xe2[1];
#define SACE(q) P01 += xe2[2*(q)]; P23 += xe2[2*(q)+1];
        REP15(SACE)
        float mean = ((P01.x + P01.y) + (P23.x + P23.y)) * (1.0f / HID);

        f2 V01 = {0.f, 0.f}, V23 = {0.f, 0.f};
        {
            f2 mn2 = {mean, mean};
#define VACE(q) { f2 a0 = xe2[2*(q)] - mn2; f2 a1 = xe2[2*(q)+1] - mn2; \
            V01 = __builtin_elementwise_fma(a0, a0, V01); \
            V23 = __builtin_elementwise_fma(a1, a1, V23); \
            xe2[2*(q)] = a0; xe2[2*(q)+1] = a1; }
            REP16(VACE)
        }
        float var  = ((V01.x + V01.y) + (V23.x + V23.y)) * (1.0f / HID);
        float rstd = 1.0f / sqrtf(var + 1e-6f);

        // ---- scale/shift + GELU (r11-verbatim) ----
        {
            const f2 rs2 = {rstd, rstd};
            const f2 kB2 = {0.044715f, 0.044715f};
            const f2 kC2 = {-1.5957691216057308f, -1.5957691216057308f};
#define GEL1(p, lss, lbv) { \
            f2 t = xe2[p] * rs2; \
            f2 g; PKFMA_GL(g, t, lss, lbv) \
            f2 g2 = g * g; f2 g3 = g2 * g; \
            f2 z = __builtin_elementwise_fma(kB2, g3, g) * kC2; \
            float e0 = __expf(z.x), e1 = __expf(z.y); \
            xe2[p].x = __fdividef(g.x, 1.0f + e0); \
            xe2[p].y = __fdividef(g.y, 1.0f + e1); }
#define GELH(h, AH) { f16s lsg; SLD16(lsg, (h)*64, lns) \
            f4 L0, L1, L2, L3; LDS4U(L0, L1, L2, L3, AH) \
            GEL1(8*(h)+0, PKW(lsg,0), SHF2(L0,0)) \
            GEL1(8*(h)+1, PKW(lsg,1), SHF2(L0,1)) \
            GEL1(8*(h)+2, PKW(lsg,2), SHF2(L1,0)) \
            GEL1(8*(h)+3, PKW(lsg,3), SHF2(L1,1)) \
            GEL1(8*(h)+4, PKW(lsg,4), SHF2(L2,0)) \
            GEL1(8*(h)+5, PKW(lsg,5), SHF2(L2,1)) \
            GEL1(8*(h)+6, PKW(lsg,6), SHF2(L3,0)) \
            GEL1(8*(h)+7, PKW(lsg,7), SHF2(L3,1)) }
            GELH(0, aln0) GELH(1, aln1) GELH(2, aln2) GELH(3, aln3)
        }

        // ---- out matmul PACKED: u2[i] = sum_p xe2[p] * owT[i].pair(p) ----
        float u[SD];
#define OUTI(i) { f16s wa, wb, wc, wd; \
        SLOAD4(wa, wb, wc, wd, owt, (i)*256, (i)*256+64, (i)*256+128, (i)*256+192) \
        f2 acc = {0.f, 0.f}; \
        AP8(OPK_E, acc, 0,  wa) AP8(OPK_E, acc, 8,  wb) \
        AP8(OPK_E, acc, 16, wc) AP8(OPK_E, acc, 24, wd) \
        u[i] = (acc.x + acc.y) + obv[i]; }
        REP7(OUTI)

        // ---- L2 normalize (identical) ----
        float ss = 0.f;
#define SSQ(i) ss = fmaf(u[i], u[i], ss);
        REP7(SSQ)
        float inv = __fdividef(1.0f, sqrtf(ss) + 1e-8f);

        // ---- damped update + convergence (identical) ----
        float dd = 0.f;
#define UPD(i) { float un = u[i] * inv; float mn = 0.5f * mu[i] + 0.5f * un; \
        float d = mn - mu[i]; dd = fmaf(d, d, dd); mu[i] = mn; }
        REP7(UPD)
        if (sqrtf(dd) < 1e-4f) conv = 1.0f;
    }

#define ST(i) out_mu[(size_t)row * SD + (i)] = mu[i];
    REP7(ST)
    out_cv[row] = conv;
}

extern "C" void kernel_launch(void* const* d_in, const int* in_sizes, int n_in,
                              void* d_out, int out_size, void* d_ws, size_t ws_size,
                              hipStream_t stream) {
    const float* s7  = (const float*)d_in[0];
    const float* w0  = (const float*)d_in[1];
    const float* b0  = (const float*)d_in[2];
    const float* lns = (const float*)d_in[3];
    const float* lnb = (const float*)d_in[4];
    const float* ow  = (const float*)d_in[5];
    const float* ob  = (const float*)d_in[6];
    const int Bn = in_sizes[0] / SD;

    float* out_mu = (float*)d_out;
    float* out_cv = out_mu + (size_t)Bn * SD;
    float* owt    = (float*)d_ws;            // 448 floats = 1792 B scratch

    hipLaunchKernelGGL(transpose_ow_kernel, dim3(1), dim3(512), 0, stream, ow, owt);

    const int block = 256;
    const int grid  = (Bn + block - 1) / block;
    hipLaunchKernelGGL(strange_loop_kernel, dim3(grid), dim3(block), 0, stream,
                       s7, w0, b0, lns, lnb, owt, ob, out_mu, out_cv, Bn);
}